// Round 1
// baseline (46.940 us; speedup 1.0000x reference)
//
#include <hip/hip_runtime.h>

#define HH 256
#define WW 256
#define CHUNK 1024
#define NTHREADS 256

// Per-gaussian staged record: [u, v, exp2coef, op] [r, g, b, z]
__global__ __launch_bounds__(NTHREADS) void render_kernel(
    const float* __restrict__ means,
    const float* __restrict__ colors,
    const float* __restrict__ opacity,
    const float* __restrict__ scales,
    const float* __restrict__ K,
    const float* __restrict__ M,   // world_to_camera, 4x4 row-major
    float* __restrict__ out,
    int N)
{
    __shared__ float4 sg[CHUNK * 2];

    const int tid = threadIdx.x;
    const int p   = blockIdx.x * NTHREADS + tid;   // pixel index, y*W+x
    const float x = (float)(p & (WW - 1));
    const float y = (float)(p >> 8);

    // Broadcast camera params (wave-uniform scalar loads)
    const float m00 = M[0],  m01 = M[1],  m02 = M[2],  m03 = M[3];
    const float m10 = M[4],  m11 = M[5],  m12 = M[6],  m13 = M[7];
    const float m20 = M[8],  m21 = M[9],  m22 = M[10], m23 = M[11];
    const float fx  = K[0],  sk  = K[1],  cx  = K[2];
    const float fy  = K[4],  cy  = K[5];

    float s  = 0.f;   // sum alpha
    float ar = 0.f, ag = 0.f, ab = 0.f;  // sum alpha*color
    float az = 0.f;   // sum alpha*z

    for (int base = 0; base < N; base += CHUNK) {
        const int cnt = min(CHUNK, N - base);

        __syncthreads();  // protect previous chunk's reads before overwrite
        // Stage this chunk: each thread projects a few gaussians into LDS
        for (int i = tid; i < cnt; i += NTHREADS) {
            const int n = base + i;
            const float wx = means[3 * n + 0];
            const float wy = means[3 * n + 1];
            const float wz = means[3 * n + 2];
            const float px = m00 * wx + m01 * wy + m02 * wz + m03;
            const float py = m10 * wx + m11 * wy + m12 * wz + m13;
            const float pz = m20 * wx + m21 * wy + m22 * wz + m23;
            const float rz = 1.0f / pz;
            float u = (fx * px + sk * py + cx * pz) * rz;
            float v = (fy * py + cy * pz) * rz;
            const bool valid = (pz > 1e-4f)
                            && (u >= -(float)WW) && (u <= 2.0f * (float)WW)
                            && (v >= -(float)HH) && (v <= 2.0f * (float)HH);
            float op = valid ? opacity[n] : 0.0f;
            const float sig = fmaxf(scales[n] * 256.0f, 1.0f);  // max(H,W)=256
            // exp(-0.5*r2/sig^2) = exp2(r2 * coef), coef = -0.5*log2(e)/sig^2
            float coef = -0.72134752044448170368f / (sig * sig);
            if (!valid) { u = 0.f; v = 0.f; coef = 0.f; }  // keep NaN/inf out
            sg[2 * i + 0] = make_float4(u, v, coef, op);
            sg[2 * i + 1] = make_float4(colors[3 * n + 0], colors[3 * n + 1],
                                        colors[3 * n + 2], pz);
        }
        __syncthreads();

        // Accumulate this chunk over all gaussians (LDS broadcast reads)
        #pragma unroll 8
        for (int n = 0; n < cnt; ++n) {
            const float4 a = sg[2 * n + 0];
            const float4 c = sg[2 * n + 1];
            const float dx = x - a.x;
            const float dy = y - a.y;
            const float r2 = dx * dx + dy * dy;
            const float e  = exp2f(r2 * a.z);
            const float alpha = fminf(a.w * e, 0.95f);
            s  += alpha;
            ar += alpha * c.x;
            ag += alpha * c.y;
            ab += alpha * c.z;
            az += alpha * c.w;
        }
    }

    // Epilogue: weights = alpha/(S+eps) folded into the accumulated sums
    const float inv   = 1.0f / (s + 1e-6f);
    const float accum = fminf(s, 1.0f);   // s >= 0 always
    const float bg    = 1.0f - accum;
    const float R = fminf(fmaxf(ar * inv * accum + bg, 0.0f), 1.0f);
    const float G = fminf(fmaxf(ag * inv * accum + bg, 0.0f), 1.0f);
    const float B = fminf(fmaxf(ab * inv * accum + bg, 0.0f), 1.0f);

    const int HW = HH * WW;
    out[0 * HW + p] = R;
    out[1 * HW + p] = G;
    out[2 * HW + p] = B;
    out[3 * HW + p] = accum;
    out[4 * HW + p] = az * inv;   // depth (no clip, no background in ref)
}

extern "C" void kernel_launch(void* const* d_in, const int* in_sizes, int n_in,
                              void* d_out, int out_size, void* d_ws, size_t ws_size,
                              hipStream_t stream) {
    const float* means      = (const float*)d_in[0];
    const float* colors     = (const float*)d_in[1];
    const float* opacity    = (const float*)d_in[2];
    const float* scales     = (const float*)d_in[3];
    const float* intrinsics = (const float*)d_in[4];
    const float* w2c        = (const float*)d_in[5];
    float* out = (float*)d_out;

    const int N  = in_sizes[0] / 3;
    const int HW = out_size / 5;           // 65536
    const int nblocks = HW / NTHREADS;     // 256

    render_kernel<<<nblocks, NTHREADS, 0, stream>>>(
        means, colors, opacity, scales, intrinsics, w2c, out, N);
}

// Round 2
// 35.099 us; speedup vs baseline: 1.3374x; 1.3374x over previous
//
#include <hip/hip_runtime.h>

#define HH 256
#define WW 256
#define NTHREADS 256
#define MAXCHUNK 256
#define HWPIX (HH * WW)

// ---------------------------------------------------------------------------
// Partial-sum kernel: blockIdx.x = pixel group (256 px), blockIdx.y = gaussian
// slice. Each block projects its slice of gaussians into LDS, then every
// thread (one pixel) accumulates 5 linear sums: S=sum(a), sum(a*rgb), sum(a*z).
// Staged record per gaussian: [u, v, exp2coef, log2(op)] [r, g, b, z]
// alpha = min( exp2(r2*coef + log2(op)), 0.95 )
// ---------------------------------------------------------------------------
__global__ __launch_bounds__(NTHREADS) void partial_kernel(
    const float* __restrict__ means,
    const float* __restrict__ colors,
    const float* __restrict__ opacity,
    const float* __restrict__ scales,
    const float* __restrict__ K,
    const float* __restrict__ M,
    float* __restrict__ ws,
    int N, int nslice)
{
    __shared__ float4 sg[MAXCHUNK * 2];

    const int tid   = threadIdx.x;
    const int p     = blockIdx.x * NTHREADS + tid;
    const int slice = blockIdx.y;
    const float x = (float)(p & (WW - 1));
    const float y = (float)(p >> 8);

    const float m00 = M[0],  m01 = M[1],  m02 = M[2],  m03 = M[3];
    const float m10 = M[4],  m11 = M[5],  m12 = M[6],  m13 = M[7];
    const float m20 = M[8],  m21 = M[9],  m22 = M[10], m23 = M[11];
    const float fx  = K[0],  sk  = K[1],  cx  = K[2];
    const float fy  = K[4],  cy  = K[5];

    const int chunk = (N + nslice - 1) / nslice;
    const int g0 = slice * chunk;
    const int g1 = min(N, g0 + chunk);

    float s  = 0.f;
    float ar = 0.f, ag = 0.f, ab = 0.f;
    float az = 0.f;

    for (int base = g0; base < g1; base += MAXCHUNK) {
        const int cnt = min(MAXCHUNK, g1 - base);

        __syncthreads();
        for (int i = tid; i < cnt; i += NTHREADS) {
            const int n = base + i;
            const float wx = means[3 * n + 0];
            const float wy = means[3 * n + 1];
            const float wz = means[3 * n + 2];
            const float px = m00 * wx + m01 * wy + m02 * wz + m03;
            const float py = m10 * wx + m11 * wy + m12 * wz + m13;
            const float pz = m20 * wx + m21 * wy + m22 * wz + m23;
            const float rz = 1.0f / pz;
            float u = (fx * px + sk * py + cx * pz) * rz;
            float v = (fy * py + cy * pz) * rz;
            const bool valid = (pz > 1e-4f)
                            && (u >= -(float)WW) && (u <= 2.0f * (float)WW)
                            && (v >= -(float)HH) && (v <= 2.0f * (float)HH);
            const float op = valid ? opacity[n] : 0.0f;
            const float sig = fmaxf(scales[n] * 256.0f, 1.0f);
            float coef = -0.72134752044448170368f / (sig * sig); // -0.5*log2e/sig^2
            const float lop = __log2f(op);                       // op=0 -> -inf -> exp2=0
            if (!valid) { u = 0.f; v = 0.f; coef = 0.f; }
            sg[2 * i + 0] = make_float4(u, v, coef, lop);
            sg[2 * i + 1] = make_float4(colors[3 * n + 0], colors[3 * n + 1],
                                        colors[3 * n + 2], pz);
        }
        __syncthreads();

        #pragma unroll 8
        for (int n = 0; n < cnt; ++n) {
            const float4 a = sg[2 * n + 0];
            const float4 c = sg[2 * n + 1];
            const float dx = x - a.x;
            const float dy = y - a.y;
            float r2 = dx * dx;
            r2 = fmaf(dy, dy, r2);
            const float e = exp2f(fmaf(r2, a.z, a.w));
            const float alpha = fminf(e, 0.95f);
            s  += alpha;
            ar = fmaf(alpha, c.x, ar);
            ag = fmaf(alpha, c.y, ag);
            ab = fmaf(alpha, c.z, ab);
            az = fmaf(alpha, c.w, az);
        }
    }

    float* o = ws + (size_t)(slice * 5) * HWPIX + p;
    o[0 * HWPIX] = s;
    o[1 * HWPIX] = ar;
    o[2 * HWPIX] = ag;
    o[3 * HWPIX] = ab;
    o[4 * HWPIX] = az;
}

// ---------------------------------------------------------------------------
// Epilogue: reduce slices, normalize, background-composite, clip, store.
// ---------------------------------------------------------------------------
__global__ __launch_bounds__(NTHREADS) void epilogue_kernel(
    const float* __restrict__ ws, float* __restrict__ out, int nslice)
{
    const int p = blockIdx.x * NTHREADS + threadIdx.x;
    float s = 0.f, ar = 0.f, ag = 0.f, ab = 0.f, az = 0.f;
    for (int sl = 0; sl < nslice; ++sl) {
        const float* o = ws + (size_t)(sl * 5) * HWPIX + p;
        s  += o[0 * HWPIX];
        ar += o[1 * HWPIX];
        ag += o[2 * HWPIX];
        ab += o[3 * HWPIX];
        az += o[4 * HWPIX];
    }
    const float inv   = 1.0f / (s + 1e-6f);
    const float accum = fminf(s, 1.0f);
    const float bg    = 1.0f - accum;
    const float R = fminf(fmaxf(fmaf(ar * inv, accum, bg), 0.0f), 1.0f);
    const float G = fminf(fmaxf(fmaf(ag * inv, accum, bg), 0.0f), 1.0f);
    const float B = fminf(fmaxf(fmaf(ab * inv, accum, bg), 0.0f), 1.0f);
    out[0 * HWPIX + p] = R;
    out[1 * HWPIX + p] = G;
    out[2 * HWPIX + p] = B;
    out[3 * HWPIX + p] = accum;
    out[4 * HWPIX + p] = az * inv;
}

// ---------------------------------------------------------------------------
// Fallback fused kernel (used only if ws can't hold even one slice's partials)
// ---------------------------------------------------------------------------
__global__ __launch_bounds__(NTHREADS) void fused_kernel(
    const float* __restrict__ means,
    const float* __restrict__ colors,
    const float* __restrict__ opacity,
    const float* __restrict__ scales,
    const float* __restrict__ K,
    const float* __restrict__ M,
    float* __restrict__ out,
    int N)
{
    __shared__ float4 sg[MAXCHUNK * 2];
    const int tid = threadIdx.x;
    const int p   = blockIdx.x * NTHREADS + tid;
    const float x = (float)(p & (WW - 1));
    const float y = (float)(p >> 8);

    const float m00 = M[0],  m01 = M[1],  m02 = M[2],  m03 = M[3];
    const float m10 = M[4],  m11 = M[5],  m12 = M[6],  m13 = M[7];
    const float m20 = M[8],  m21 = M[9],  m22 = M[10], m23 = M[11];
    const float fx  = K[0],  sk  = K[1],  cx  = K[2];
    const float fy  = K[4],  cy  = K[5];

    float s = 0.f, ar = 0.f, ag = 0.f, ab = 0.f, az = 0.f;

    for (int base = 0; base < N; base += MAXCHUNK) {
        const int cnt = min(MAXCHUNK, N - base);
        __syncthreads();
        for (int i = tid; i < cnt; i += NTHREADS) {
            const int n = base + i;
            const float wx = means[3 * n + 0];
            const float wy = means[3 * n + 1];
            const float wz = means[3 * n + 2];
            const float px = m00 * wx + m01 * wy + m02 * wz + m03;
            const float py = m10 * wx + m11 * wy + m12 * wz + m13;
            const float pz = m20 * wx + m21 * wy + m22 * wz + m23;
            const float rz = 1.0f / pz;
            float u = (fx * px + sk * py + cx * pz) * rz;
            float v = (fy * py + cy * pz) * rz;
            const bool valid = (pz > 1e-4f)
                            && (u >= -(float)WW) && (u <= 2.0f * (float)WW)
                            && (v >= -(float)HH) && (v <= 2.0f * (float)HH);
            const float op = valid ? opacity[n] : 0.0f;
            const float sig = fmaxf(scales[n] * 256.0f, 1.0f);
            float coef = -0.72134752044448170368f / (sig * sig);
            const float lop = __log2f(op);
            if (!valid) { u = 0.f; v = 0.f; coef = 0.f; }
            sg[2 * i + 0] = make_float4(u, v, coef, lop);
            sg[2 * i + 1] = make_float4(colors[3 * n + 0], colors[3 * n + 1],
                                        colors[3 * n + 2], pz);
        }
        __syncthreads();
        #pragma unroll 8
        for (int n = 0; n < cnt; ++n) {
            const float4 a = sg[2 * n + 0];
            const float4 c = sg[2 * n + 1];
            const float dx = x - a.x;
            const float dy = y - a.y;
            float r2 = dx * dx;
            r2 = fmaf(dy, dy, r2);
            const float e = exp2f(fmaf(r2, a.z, a.w));
            const float alpha = fminf(e, 0.95f);
            s  += alpha;
            ar = fmaf(alpha, c.x, ar);
            ag = fmaf(alpha, c.y, ag);
            ab = fmaf(alpha, c.z, ab);
            az = fmaf(alpha, c.w, az);
        }
    }

    const float inv   = 1.0f / (s + 1e-6f);
    const float accum = fminf(s, 1.0f);
    const float bg    = 1.0f - accum;
    out[0 * HWPIX + p] = fminf(fmaxf(fmaf(ar * inv, accum, bg), 0.0f), 1.0f);
    out[1 * HWPIX + p] = fminf(fmaxf(fmaf(ag * inv, accum, bg), 0.0f), 1.0f);
    out[2 * HWPIX + p] = fminf(fmaxf(fmaf(ab * inv, accum, bg), 0.0f), 1.0f);
    out[3 * HWPIX + p] = accum;
    out[4 * HWPIX + p] = az * inv;
}

extern "C" void kernel_launch(void* const* d_in, const int* in_sizes, int n_in,
                              void* d_out, int out_size, void* d_ws, size_t ws_size,
                              hipStream_t stream) {
    const float* means      = (const float*)d_in[0];
    const float* colors     = (const float*)d_in[1];
    const float* opacity    = (const float*)d_in[2];
    const float* scales     = (const float*)d_in[3];
    const float* intrinsics = (const float*)d_in[4];
    const float* w2c        = (const float*)d_in[5];
    float* out = (float*)d_out;
    float* ws  = (float*)d_ws;

    const int N = in_sizes[0] / 3;
    const int npixblocks = HWPIX / NTHREADS;   // 256

    int nslice = 8;
    while (nslice > 1 && (size_t)nslice * 5 * HWPIX * 4 > ws_size) nslice >>= 1;

    if ((size_t)5 * HWPIX * 4 > ws_size) {
        // ws too small even for one slice: fused path
        fused_kernel<<<npixblocks, NTHREADS, 0, stream>>>(
            means, colors, opacity, scales, intrinsics, w2c, out, N);
        return;
    }

    dim3 grid(npixblocks, nslice);
    partial_kernel<<<grid, NTHREADS, 0, stream>>>(
        means, colors, opacity, scales, intrinsics, w2c, ws, N, nslice);
    epilogue_kernel<<<npixblocks, NTHREADS, 0, stream>>>(ws, out, nslice);
}